// Round 10
// baseline (94.721 us; speedup 1.0000x reference)
//
#include <hip/hip_runtime.h>
#include <hip/hip_bf16.h>

#define N_NODES 8192
#define F_IN 256
#define F_OUT 128

#define SPLITK 4
#define KQ (N_NODES / SPLITK)   // 2048
#define BK 64
#define NT (KQ / BK)            // 32
#define ABYTES 8192             // A tile: 32 rows x 64 k x fp32
#define BBYTES 16384            // B tile: 128 f x 64 k x bf16
#define AREG (3 * ABYTES)       // A: 3 buffers (depth-2)
#define LDS_TOTAL (AREG + 2 * BBYTES)   // 56 KB -> 2 blocks/CU

typedef __attribute__((ext_vector_type(4))) float f32x4;
typedef __attribute__((ext_vector_type(8))) short bf16x8;
typedef __attribute__((ext_vector_type(2))) unsigned int u32x2;

static __device__ __forceinline__ short bfr(float x) {
    __hip_bfloat16 h = __float2bfloat16(x);   // RNE
    union { __hip_bfloat16 h; short s; } u; u.h = h;
    return u.s;
}

static __device__ __forceinline__ void gload16(const void* g, void* l) {
    __builtin_amdgcn_global_load_lds(
        (const __attribute__((address_space(1))) unsigned int*)g,
        (__attribute__((address_space(3))) unsigned int*)l, 16, 0, 0);
}

// Kernel 1: support^T[f][n] = sum_k X[n][k] * W[k][f]   (fp32 accum -> bf16)
__global__ __launch_bounds__(256) void support_kernel(
        const float* __restrict__ X, const float* __restrict__ W,
        unsigned short* __restrict__ supT) {
    __shared__ float Xs[32][68];
    __shared__ float Ws[64][128];
    const int t = threadIdx.x;
    const int n0 = blockIdx.x * 32;
    const int tc = t & 31;
    const int tr = t >> 5;
    float acc[4][4];
    #pragma unroll
    for (int i = 0; i < 4; ++i)
        #pragma unroll
        for (int j = 0; j < 4; ++j) acc[i][j] = 0.f;

    for (int k0 = 0; k0 < F_IN; k0 += 64) {
        __syncthreads();
        {
            const int r = t >> 3, kc = (t & 7) * 8;
            const float* src = X + (size_t)(n0 + r) * F_IN + k0 + kc;
            f32x4 v0 = *(const f32x4*)src;
            f32x4 v1 = *(const f32x4*)(src + 4);
            *(f32x4*)&Xs[r][kc]     = v0;
            *(f32x4*)&Xs[r][kc + 4] = v1;
        }
        {
            const int col = t & 127, kb = t >> 7;
            #pragma unroll
            for (int i = 0; i < 32; ++i) {
                const int k = kb + i * 2;
                Ws[k][col] = W[(size_t)(k0 + k) * F_OUT + col];
            }
        }
        __syncthreads();
        #pragma unroll 8
        for (int k = 0; k < 64; ++k) {
            const f32x4 b = *(const f32x4*)&Ws[k][tc * 4];
            float a[4];
            #pragma unroll
            for (int i = 0; i < 4; ++i) a[i] = Xs[tr * 4 + i][k];
            #pragma unroll
            for (int i = 0; i < 4; ++i) {
                acc[i][0] += a[i] * b.x; acc[i][1] += a[i] * b.y;
                acc[i][2] += a[i] * b.z; acc[i][3] += a[i] * b.w;
            }
        }
    }
    #pragma unroll
    for (int j = 0; j < 4; ++j) {
        const int col = tc * 4 + j;
        #pragma unroll
        for (int i = 0; i < 4; ++i) {
            supT[(size_t)col * N_NODES + n0 + tr * 4 + i] =
                (unsigned short)bfr(acc[i][j]);
        }
    }
}

// Kernel 2: out += adj[:, hK] @ support[hK]  (+bias when h==0) via HW fp32
// atomics. BM=32, BK=64, split-K=4, grid 1024 x 512 thr (8 waves 2Mx4N,
// wave = 16x32 out). Asymmetric-depth pipeline, 56 KB LDS (2 blocks/CU):
//   A (HBM): 3 buffers, staged 2 tiles ahead (1 DMA/wave/iter)
//   B (L2):  2 buffers, staged 1 tile ahead (2 DMA/wave/iter)
// Per-body issue order [B(tt+1)x2, A(tt+2)] -> fence FIFO =
// [A(tt+1), B(tt+1)x2, A(tt+2)] -> uniform vmcnt(1): tile tt+1 retired,
// A(tt+2) stays in flight across the barrier. Never drains in steady state.
__global__ __launch_bounds__(512, 4) void gcn_kernel(
        const float* __restrict__ adj, const unsigned short* __restrict__ supT,
        const float* __restrict__ bias, float* __restrict__ out) {
    __shared__ char lds[LDS_TOTAL];
    const int t = threadIdx.x;
    const int l = t & 63;
    const int w = t >> 6;                   // 0..7
    const int rb = blockIdx.x & 255;
    const int h = blockIdx.x >> 8;          // K-quarter
    const int n0 = rb * 32;
    const int k0 = h * KQ;

    // ---- staging sources (per-lane, pre-swizzled) ----
    // A: wave w stages rows 4w..4w+3; lane l -> row 4w+(l>>4), src chunk (l&15)^(row&15)
    const int rA = 4 * w + (l >> 4);
    const char* gA = (const char*)adj
        + ((size_t)(n0 + rA) * N_NODES + k0) * 4 + (((l & 15) ^ (rA & 15)) * 16);
    // B: wave w stages f rows 16w..16w+15 (two instrs, 8 rows each)
    const char* gB0 = (const char*)supT
        + ((size_t)(16 * w + (l >> 3)) * N_NODES + k0) * 2 + (((l & 7) ^ (l >> 3)) * 16);
    const char* gB1 = gB0 + (size_t)8 * N_NODES * 2;

    // wave-uniform LDS dest offsets (HW appends lane*16)
    const int a_d  = w * 1024;
    const int b_d0 = w * 2048;
    const int b_d1 = b_d0 + 1024;

    // ---- read-side offsets (region-relative) ----
    const int wm = w >> 2, wn = w & 3;
    const int aoff = (wm * 16 + (l & 15)) * 256;
    const int akey = l & 15;
    const int ac0 = (l >> 4) * 2;
    const int boff0 = (wn * 32 + (l & 15)) * 128;
    const int boff1 = boff0 + 16 * 128;
    const int bkey = l & 7;
    const int cb0 = l >> 4;

    f32x4 acc0 = {0.f,0.f,0.f,0.f}, acc1 = {0.f,0.f,0.f,0.f};

#define PK(dst, a, b) \
    asm("v_cvt_pk_bf16_f32 %0, %1, %2" : "=v"(dst) : "v"(a), "v"(b))

#define STAGE_B(BI) { \
    char* bb = &lds[AREG + (BI) * BBYTES]; \
    gload16(gB0, bb + b_d0); \
    gload16(gB1, bb + b_d1); \
    gB0 += 128; gB1 += 128; }

#define STAGE_A(AI) { \
    gload16(gA, &lds[(AI) * ABYTES] + a_d); \
    gA += 256; }

    // prologue (FIFO order): B(0)x2, A(0), A(1)
    STAGE_B(0);
    STAGE_A(0);
    STAGE_A(1);
    asm volatile("s_waitcnt vmcnt(1)" ::: "memory");
    __builtin_amdgcn_sched_barrier(0);
    __builtin_amdgcn_s_barrier();
    __builtin_amdgcn_sched_barrier(0);

    int ai = 0;                  // tt % 3
    int bi = 0;                  // tt & 1
    for (int tt = 0; tt < NT; ++tt) {
        // issue next tiles (FIFO discipline: B first, then A)
        if (tt + 1 < NT) STAGE_B(bi ^ 1);
        if (tt + 2 < NT) { const int as = (ai >= 1) ? ai - 1 : 2; STAGE_A(as); }

        const char* abuf = &lds[ai * ABYTES];
        const char* bbuf = &lds[AREG + bi * BBYTES];
        #pragma unroll
        for (int ks = 0; ks < 2; ++ks) {
            const int ca = ks * 8 + ac0;
            f32x4 alo = *(const f32x4*)(abuf + aoff + (((ca    ) ^ akey) * 16));
            f32x4 ahi = *(const f32x4*)(abuf + aoff + (((ca + 1) ^ akey) * 16));
            const int cb = ks * 4 + cb0;
            bf16x8 b0 = *(const bf16x8*)(bbuf + boff0 + ((cb ^ bkey) * 16));
            bf16x8 b1 = *(const bf16x8*)(bbuf + boff1 + ((cb ^ bkey) * 16));
            u32x2 plo, phi;
            PK(plo.x, alo.x, alo.y); PK(plo.y, alo.z, alo.w);
            PK(phi.x, ahi.x, ahi.y); PK(phi.y, ahi.z, ahi.w);
            union { u32x2 u[2]; bf16x8 v; } am;
            am.u[0] = plo; am.u[1] = phi;
            acc0 = __builtin_amdgcn_mfma_f32_16x16x32_bf16(am.v, b0, acc0, 0, 0, 0);
            acc1 = __builtin_amdgcn_mfma_f32_16x16x32_bf16(am.v, b1, acc1, 0, 0, 0);
        }

        // fence: steady vmcnt(1) (A(tt+2) stays in flight); drain at the tail
        if (tt < NT - 2) {
            asm volatile("s_waitcnt vmcnt(1)" ::: "memory");
        } else if (tt == NT - 2) {
            asm volatile("s_waitcnt vmcnt(0)" ::: "memory");
        }
        if (tt < NT - 1) {
            __builtin_amdgcn_sched_barrier(0);
            __builtin_amdgcn_s_barrier();
            __builtin_amdgcn_sched_barrier(0);
        }
        ai = (ai == 2) ? 0 : ai + 1;
        bi ^= 1;
    }
#undef STAGE_A
#undef STAGE_B
#undef PK

    // epilogue: atomic-accumulate into zeroed out; h==0 adds bias once.
    const int col = wn * 32 + (l & 15);
    const int row0 = n0 + wm * 16 + (l >> 4) * 4;
    const float bv0 = (h == 0) ? bias[col]      : 0.0f;
    const float bv1 = (h == 0) ? bias[col + 16] : 0.0f;
    #pragma unroll
    for (int i = 0; i < 4; ++i) {
        float* o = out + (size_t)(row0 + i) * F_OUT + col;
        unsafeAtomicAdd(&o[0],  acc0[i] + bv0);
        unsafeAtomicAdd(&o[16], acc1[i] + bv1);
    }
}

extern "C" void kernel_launch(void* const* d_in, const int* in_sizes, int n_in,
                              void* d_out, int out_size, void* d_ws, size_t ws_size,
                              hipStream_t stream) {
    const float* input  = (const float*)d_in[0];
    const float* adj    = (const float*)d_in[1];
    const float* weight = (const float*)d_in[2];
    const float* bias   = (const float*)d_in[3];
    float* out = (float*)d_out;
    unsigned short* supT = (unsigned short*)d_ws;           // 2 MiB

    hipMemsetAsync(d_out, 0, (size_t)out_size * sizeof(float), stream);
    support_kernel<<<N_NODES / 32, 256, 0, stream>>>(input, weight, supT);
    gcn_kernel<<<256 * SPLITK, 512, 0, stream>>>(adj, supT, bias, out);
}